// Round 7
// baseline (1017.848 us; speedup 1.0000x reference)
//
#include <hip/hip_runtime.h>
#include <hip/hip_bf16.h>
#include <math.h>

#define C_   1024
#define P_   2304      // 48*48
#define S4   331776    // 24^4

typedef __attribute__((ext_vector_type(8))) short short8;
typedef __attribute__((ext_vector_type(4))) float f32x4;
typedef __attribute__((ext_vector_type(4))) unsigned int u32x4;

__device__ inline unsigned short f2bf(float v) {
  unsigned u = __builtin_bit_cast(unsigned, v);
  u += 0x7fffu + ((u >> 16) & 1u);          // RNE
  return (unsigned short)(u >> 16);
}
__device__ inline float bf2f(unsigned short h) {
  unsigned u = ((unsigned)h) << 16;
  return __builtin_bit_cast(float, u);
}

// async global->LDS DMA, 16B per lane; LDS dest = wave-uniform base + lane*16
__device__ inline void async16(const void* g, void* l) {
  __builtin_amdgcn_global_load_lds(
      (const __attribute__((address_space(1))) unsigned int*)g,
      (__attribute__((address_space(3))) unsigned int*)l, 16, 0, 0);
}

// ---------------- K1: transpose + bf16 hi/lo split + sumsq partials --------
__global__ __launch_bounds__(256) void k_prep(
    const float* __restrict__ fA, const float* __restrict__ fB,
    unsigned short* __restrict__ TAhi, unsigned short* __restrict__ TAlo,
    unsigned short* __restrict__ TBhi, unsigned short* __restrict__ TBlo,
    float* __restrict__ part) {
  __shared__ float ld[64 * 65];
  __shared__ float pslds[512];
  const int c0 = blockIdx.x * 64, p0 = blockIdx.y * 64;
  const int fb = blockIdx.z, f = fb >> 3, b = fb & 7;
  const float* src = (f ? fB : fA) + (size_t)b * C_ * P_;
  unsigned short* Thi = (f ? TBhi : TAhi) + (size_t)b * P_ * C_;
  unsigned short* Tlo = (f ? TBlo : TAlo) + (size_t)b * P_ * C_;
  const int t = threadIdx.x;
#pragma unroll
  for (int e = 0; e < 4; ++e) {
    int cid = t + e * 256;
    int r = cid >> 4, ch = cid & 15;
    float4 v = *(const float4*)&src[(size_t)(c0 + r) * P_ + p0 + ch * 4];
    ld[r * 65 + ch * 4 + 0] = v.x;
    ld[r * 65 + ch * 4 + 1] = v.y;
    ld[r * 65 + ch * 4 + 2] = v.z;
    ld[r * 65 + ch * 4 + 3] = v.w;
  }
  __syncthreads();
#pragma unroll
  for (int e = 0; e < 2; ++e) {
    int ocid = t + e * 256;
    int pl = ocid >> 3, c8 = ocid & 7;
    unsigned short hi[8], lo[8];
    float sq = 0.f;
#pragma unroll
    for (int s = 0; s < 8; ++s) {
      float v = ld[(c8 * 8 + s) * 65 + pl];
      unsigned short h = f2bf(v);
      float rem = v - bf2f(h);
      hi[s] = h; lo[s] = f2bf(rem);
      sq = fmaf(v, v, sq);
    }
    size_t go = (size_t)(p0 + pl) * C_ + c0 + c8 * 8;
    *(uint4*)&Thi[go] = *(uint4*)hi;
    *(uint4*)&Tlo[go] = *(uint4*)lo;
    pslds[ocid] = sq;
  }
  __syncthreads();
  if (t < 64) {
    float s = 0.f;
#pragma unroll
    for (int c8 = 0; c8 < 8; ++c8) s += pslds[t * 8 + c8];
    part[((size_t)fb * 16 + blockIdx.x) * P_ + p0 + t] = s;
  }
}

// ---------------- K2: finalize inverse norms -------------------------------
__global__ void k_invnorm(const float* __restrict__ part, float* __restrict__ inv) {
  int p = blockIdx.x * 256 + threadIdx.x;
  int fb = blockIdx.y;
  float s = 1e-6f;
  for (int ct = 0; ct < 16; ++ct) s += part[((size_t)fb * 16 + ct) * P_ + p];
  inv[(size_t)fb * P_ + p] = 1.0f / sqrtf(s);
}

// ---------------- K3: bf16x3 MFMA correlation + relu/norm/4D-maxpool -------
// v5 structure (R5, verified): 192x96 tile, XOR-chunk swizzled staging,
// pre-reduced epilogue. Unchanged.
__global__ __launch_bounds__(256, 3) void k_corr_mfma(
    const unsigned short* __restrict__ TAhi_, const unsigned short* __restrict__ TAlo_,
    const unsigned short* __restrict__ TBhi_, const unsigned short* __restrict__ TBlo_,
    const float* __restrict__ invn, float* __restrict__ pooled) {
  __shared__ __align__(16) char lds_raw[36864];   // 576 rows x 64 B; epi overlay
  float* epi = (float*)lds_raw;                   // [96][50] f32 = 19200 B

  const int b = blockIdx.y;
  const size_t tb = (size_t)b * P_ * C_;
  const unsigned short* TAhi = TAhi_ + tb;
  const unsigned short* TAlo = TAlo_ + tb;
  const unsigned short* TBhi = TBhi_ + tb;
  const unsigned short* TBlo = TBlo_ + tb;
  float* out = pooled + (size_t)b * S4;

  const int g = blockIdx.x;                 // 0..287
  const int xcd = g & 7, idx = g >> 3;      // idx 0..35
  const int ti = (xcd & 1) * 6 + idx % 6;   // 0..11
  const int tj = (xcd >> 1) * 6 + idx / 6;  // 0..23
  const int p0 = ti * 192, q0 = tj * 96;
  const int t = threadIdx.x;
  const int lane = t & 63, w = t >> 6;
  const int wr = w >> 1, wc = w & 1;
  const int m15 = lane & 15, q4 = lane >> 4;
  const int laneoff = (q4 ^ ((m15 >> 1) & 3)) * 16;

  f32x4 acc[6][3];
#pragma unroll
  for (int a = 0; a < 6; ++a)
#pragma unroll
    for (int c = 0; c < 3; ++c) acc[a][c] = (f32x4){0.f, 0.f, 0.f, 0.f};

  const unsigned short* gld[9];
  int ldsb[9];
#pragma unroll
  for (int e = 0; e < 9; ++e) {
    int chunk = (w * 9 + e) * 64 + lane;    // 0..2303
    int row = chunk >> 2, cpos = chunk & 3;
    int cglob = cpos ^ ((row >> 1) & 3);
    const unsigned short* bp; int roff;
    if (row < 192)      { bp = TAhi; roff = p0 + row; }
    else if (row < 384) { bp = TAlo; roff = p0 + row - 192; }
    else if (row < 480) { bp = TBhi; roff = q0 + row - 384; }
    else                { bp = TBlo; roff = q0 + row - 480; }
    gld[e] = bp + (size_t)roff * C_ + cglob * 8;
    ldsb[e] = (w * 9 + e) * 1024;
  }

  auto STAGE = [&](int kt) {
#pragma unroll
    for (int e = 0; e < 9; ++e)
      async16(gld[e] + kt, lds_raw + ldsb[e]);
  };

  for (int kt = 0; kt < C_; kt += 32) {
    __syncthreads();
    STAGE(kt);
    asm volatile("s_waitcnt vmcnt(0)" ::: "memory");
    __syncthreads();

    const char* buf = lds_raw;
    short8 bh[3], bl[3];
#pragma unroll
    for (int c = 0; c < 3; ++c) {
      int rB = (384 + wc * 48 + c * 16 + m15) * 64;
      bh[c] = *(const short8*)(buf + rB + laneoff);
      bl[c] = *(const short8*)(buf + rB + 6144 + laneoff);
    }
#pragma unroll
    for (int a = 0; a < 6; ++a) {
      int rA = (wr * 96 + a * 16 + m15) * 64;
      short8 ah = *(const short8*)(buf + rA + laneoff);
      short8 al = *(const short8*)(buf + rA + 12288 + laneoff);
#pragma unroll
      for (int c = 0; c < 3; ++c)
        acc[a][c] = __builtin_amdgcn_mfma_f32_16x16x32_bf16(ah, bh[c], acc[a][c], 0, 0, 0);
#pragma unroll
      for (int c = 0; c < 3; ++c)
        acc[a][c] = __builtin_amdgcn_mfma_f32_16x16x32_bf16(ah, bl[c], acc[a][c], 0, 0, 0);
#pragma unroll
      for (int c = 0; c < 3; ++c)
        acc[a][c] = __builtin_amdgcn_mfma_f32_16x16x32_bf16(al, bh[c], acc[a][c], 0, 0, 0);
    }
  }
  __syncthreads();

  const float* invA = invn + (size_t)b * P_;
  const float* invB = invn + (size_t)(8 + b) * P_;
  float ibv[3];
#pragma unroll
  for (int c = 0; c < 3; ++c) ibv[c] = invB[q0 + wc * 48 + c * 16 + m15];
#pragma unroll
  for (int a = 0; a < 6; ++a) {
    float4 ia = *(const float4*)&invA[p0 + wr * 96 + a * 16 + q4 * 4];
    int h_local = wr * 2 + (a >= 3 ? 1 : 0);
    int wbase = (a % 3) * 8 + q4 * 2;
#pragma unroll
    for (int c = 0; c < 3; ++c) {
      float v0 = acc[a][c][0] * ia.x * ibv[c];
      float v1 = acc[a][c][1] * ia.y * ibv[c];
      float v2 = acc[a][c][2] * ia.z * ibv[c];
      float v3 = acc[a][c][3] * ia.w * ibv[c];
      float m0 = fmaxf(v0, v1), m1 = fmaxf(v2, v3);
      m0 = fmaxf(m0, __shfl_xor(m0, 1, 64));
      m1 = fmaxf(m1, __shfl_xor(m1, 1, 64));
      if (!(m15 & 1)) {
        int ql2 = wc * 24 + c * 8 + (m15 >> 1);
        epi[(h_local * 24 + wbase + 0) * 50 + ql2] = m0;
        epi[(h_local * 24 + wbase + 1) * 50 + ql2] = m1;
      }
    }
  }
  __syncthreads();

  for (int ix = t; ix < 1152; ix += 256) {
    int orow = ix / 24, ocol = ix % 24;
    int dlt = orow / 24, wp = orow % 24;
    const float* r0 = &epi[((dlt * 2 + 0) * 24 + wp) * 50];
    const float* r1 = &epi[((dlt * 2 + 1) * 24 + wp) * 50];
    float m = fmaxf(fmaxf(r0[ocol], r0[24 + ocol]),
                    fmaxf(r1[ocol], r1[24 + ocol]));
    float r = fmaxf(m, 0.f);
    float v = r / sqrtf(r * r + 1e-6f);
    out[(size_t)(ti * 48 + orow) * 576 + tj * 24 + ocol] = v;
  }
}

// ---------------- K4a: row max (over kl, per ij) ---------------------------
__global__ void k_rowmax(const float* __restrict__ x, float* __restrict__ amax) {
  int row = blockIdx.x;
  const float* r = x + (size_t)row * 576;
  float m = -1e30f;
  for (int e = threadIdx.x; e < 576; e += 64) m = fmaxf(m, r[e]);
  for (int off = 32; off > 0; off >>= 1) m = fmaxf(m, __shfl_down(m, off, 64));
  if (threadIdx.x == 0) amax[row] = m;
}

// ---------------- K4b: col max (over ij, per kl) ---------------------------
__global__ void k_colmax(const float* __restrict__ x, float* __restrict__ bmax) {
  __shared__ float pl[4][64];
  int b = blockIdx.x, klc = blockIdx.y * 64;
  int t = threadIdx.x;
  int kl = klc + (t & 63), seg = t >> 6;
  const float* xb = x + (size_t)b * S4;
  float m = -1e30f;
  for (int ij = seg * 144; ij < (seg + 1) * 144; ++ij)
    m = fmaxf(m, xb[(size_t)ij * 576 + kl]);
  pl[seg][t & 63] = m;
  __syncthreads();
  if (t < 64) {
    float r = fmaxf(fmaxf(pl[0][t], pl[1][t]), fmaxf(pl[2][t], pl[3][t]));
    bmax[b * 576 + klc + t] = r;
  }
}

// ---------------- K5: mutual matching elementwise --------------------------
__global__ void k_mm_apply(const float* __restrict__ x,
                           const float* __restrict__ amax,
                           const float* __restrict__ bmax,
                           float* __restrict__ y) {
  int i = blockIdx.x * 256 + threadIdx.x;
  int b = i / S4, r = i % S4;
  int ij = r / 576, kl = r % 576;
  float c = x[i];
  y[i] = c * (c / (amax[b * 576 + ij] + 1e-5f)) * (c / (bmax[b * 576 + kl] + 1e-5f));
}

// ---------------- K7: conv1 (CIN=1, COUT=10) -> packed halo layout ---------
__global__ __launch_bounds__(192, 4) void k_conv1_pack(
    const float* __restrict__ x, const float* __restrict__ w,
    const float* __restrict__ bias, unsigned int* __restrict__ C1p) {
  __shared__ float tile[9 * 702];
  const float* xb = x + (size_t)S4 * blockIdx.y;
  unsigned int* yb = C1p + ((size_t)blockIdx.y * 576 + blockIdx.x) * 6912;
  const int ij = blockIdx.x;
  const int i = ij / 24, j = ij % 24;
  const int t = threadIdx.x;
  const int k = t >> 3;
  const int l0 = (t & 7) * 3;

  if (t < 152) yb[6760 + t] = 0u;
  if (t < 100) {
    int kk, ll;
    if (t < 26)      { kk = 0;          ll = t; }
    else if (t < 52) { kk = 25;         ll = t - 26; }
    else if (t < 76) { kk = t - 52 + 1; ll = 0; }
    else             { kk = t - 76 + 1; ll = 25; }
    unsigned int* p = yb + (kk * 26 + ll) * 10;
#pragma unroll
    for (int q = 0; q < 10; ++q) p[q] = 0u;
  }

  int soff[4]; bool eok[4], klok[4]; int eidx[4];
#pragma unroll
  for (int q = 0; q < 4; ++q) {
    int e = t + q * 192;
    eidx[q] = e; eok[q] = (e < 702);
    int row = e / 27, col = e % 27;
    klok[q] = (row >= 1 && row < 25 && col >= 1 && col < 25);
    soff[q] = (row - 1) * 24 + (col - 1);
  }

  float acc[10][3];
#pragma unroll
  for (int co = 0; co < 10; ++co)
#pragma unroll
    for (int oo = 0; oo < 3; ++oo) acc[co][oo] = 0.f;

#pragma unroll
  for (int pln = 0; pln < 9; ++pln) {
    int ii = i + pln / 3 - 1, jj = j + pln % 3 - 1;
    const bool slab_ok = (ii >= 0 && ii < 24 && jj >= 0 && jj < 24);
    const float* src = xb + (size_t)(ii * 24 + jj) * 576;
#pragma unroll
    for (int q = 0; q < 4; ++q) {
      if (eok[q]) {
        float v = 0.f;
        if (slab_ok && klok[q]) v = src[soff[q]];
        tile[pln * 702 + eidx[q]] = v;
      }
    }
  }
  __syncthreads();
#pragma unroll
  for (int pln = 0; pln < 9; ++pln) {
    const float* base = &tile[pln * 702 + k * 27 + l0];
#pragma unroll
    for (int dk = 0; dk < 3; ++dk) {
      float c0 = base[dk * 27 + 0], c1 = base[dk * 27 + 1],
            c2 = base[dk * 27 + 2], c3 = base[dk * 27 + 3],
            c4 = base[dk * 27 + 4];
#pragma unroll
      for (int co = 0; co < 10; ++co) {
        const float* wr = w + (size_t)co * 81 + pln * 9 + dk * 3;
        float w0 = wr[0], w1 = wr[1], w2v = wr[2];
        acc[co][0] = fmaf(w0, c0, acc[co][0]);
        acc[co][0] = fmaf(w1, c1, acc[co][0]);
        acc[co][0] = fmaf(w2v, c2, acc[co][0]);
        acc[co][1] = fmaf(w0, c1, acc[co][1]);
        acc[co][1] = fmaf(w1, c2, acc[co][1]);
        acc[co][1] = fmaf(w2v, c3, acc[co][1]);
        acc[co][2] = fmaf(w0, c2, acc[co][2]);
        acc[co][2] = fmaf(w1, c3, acc[co][2]);
        acc[co][2] = fmaf(w2v, c4, acc[co][2]);
      }
    }
  }
#pragma unroll
  for (int oo = 0; oo < 3; ++oo) {
    unsigned int* baseo = yb + ((k + 1) * 26 + (l0 + oo + 1)) * 10;
#pragma unroll
    for (int co = 0; co < 10; ++co) {
      float v = fmaxf(acc[co][oo] + bias[co], 0.f);
      unsigned short hi = f2bf(v);
      unsigned short lo = f2bf(v - bf2f(hi));
      baseo[co] = ((unsigned)hi << 16) | (unsigned)lo;
    }
  }
}

// ---------------- K8: pack conv2 weights (interleaved-kappa', 2 packs) -----
// P1/P2: [30 taps][2 half][16 n][32 kappa'] ushort. Real k = h*16 + kp/2.
// P1[kp] = Wh[k] (both parities)   -> MFMA gives (lo+hi)*Wh = A*Wh
// P2[kp] = odd(kp) ? Wl[k] : 0     -> MFMA gives hi*Wl
// Sum == the proven 3-term bf16x3 decomposition, zero unpack VALU in conv2.
__global__ void k_packw2(const float* __restrict__ w2,
                         unsigned short* __restrict__ P1,
                         unsigned short* __restrict__ P2) {
  int idx = blockIdx.x * 256 + threadIdx.x;
  if (idx >= 30720) return;
  int tap = idx >> 10;            // 0..29
  int h   = (idx >> 9) & 1;
  int n   = (idx >> 5) & 15;
  int kp  = idx & 31;
  int k   = h * 16 + (kp >> 1);   // real kappa 0..31
  float v = 0.f;
  if (tap < 27 && n < 10 && k < 30) {
    int ci = k % 10, dl = k / 10;
    v = w2[(size_t)(n * 10 + ci) * 81 + tap * 3 + dl];
  }
  unsigned short hi = f2bf(v);
  unsigned short lo = f2bf(v - bf2f(hi));
  P1[idx] = hi;
  P2[idx] = (kp & 1) ? lo : (unsigned short)0;
}

// ---------------- K8b: pack conv3 weights (R5 layout, perms path) ----------
// Bh/Bl [9 slabs][16 n][32 kappa]; n = dk (3 used), kappa = dl*10+ci.
__global__ void k_packw3(const float* __restrict__ w3,
                         unsigned short* __restrict__ Bh,
                         unsigned short* __restrict__ Bl) {
  int idx = blockIdx.x * 256 + threadIdx.x;
  if (idx >= 4608) return;
  int s = idx >> 9;            // slab (di,dj) 0..8
  int n = (idx >> 5) & 15;     // dk
  int kap = idx & 31;
  float v = 0.f;
  if (n < 3 && kap < 30) {
    int ci = kap % 10, dl = kap / 10;
    v = w3[(size_t)ci * 81 + s * 9 + n * 3 + dl];
  }
  unsigned short hi = f2bf(v);
  unsigned short lo = f2bf(v - bf2f(hi));
  Bh[idx] = hi; Bl[idx] = lo;
}

// ---------------- K9: conv2 (10->10) MFMA, zero-unpack interleaved A -------
// A-frags read DIRECTLY from the packed LDS slab (interleaved lo/hi ==
// bf16 kappa' vector); per (mi,dk): 4x 8B LDS reads (same bytes/addresses
// as the R5 perm path) + 4 MFMAs, 0 perms. HARDENED SYNC: vmcnt(7) drains
// STAGE(s) AND all 12 current B-loads under any issue order; only
// STAGE(s+1) stays in flight. Tail vmcnt(0).
__global__ __launch_bounds__(256, 2) void k_conv2_mfma(
    const unsigned int* __restrict__ C1p,
    const unsigned short* __restrict__ Wp1, const unsigned short* __restrict__ Wp2,
    const float* __restrict__ bias, unsigned int* __restrict__ C2p) {
  __shared__ __align__(16) unsigned int lds[2 * 7168];
  const int b = blockIdx.y, ij = blockIdx.x;
  const int i = ij / 24, j = ij % 24;
  const int t = threadIdx.x, lane = t & 63, w = t >> 6;
  const int m15 = lane & 15, q4 = lane >> 4;

  // zero halo border + pad of own output slab (block-owned, disjoint addrs)
  unsigned int* yb = C2p + ((size_t)b * 576 + ij) * 6912;
  if (t < 152) yb[6760 + t] = 0u;
  if (t < 100) {
    int kk, ll;
    if (t < 26)      { kk = 0;          ll = t; }
    else if (t < 52) { kk = 25;         ll = t - 26; }
    else if (t < 76) { kk = t - 52 + 1; ll = 0; }
    else             { kk = t - 76 + 1; ll = 25; }
    unsigned int* p = yb + (kk * 26 + ll) * 10;
#pragma unroll
    for (int q = 0; q < 10; ++q) p[q] = 0u;
  }

  int rowb[9];
#pragma unroll
  for (int mi = 0; mi < 9; ++mi) {
    int kl = (w * 9 + mi) * 16 + m15;
    int kk = kl / 24, ll = kl % 24;
    rowb[mi] = ((kk + 1) * 26 + ll) * 10;
  }

  const unsigned int* sptr[9]; int tb[9];
#pragma unroll
  for (int s = 0; s < 9; ++s) {
    int di = s / 3 - 1, dj = s % 3 - 1;
    int ii = i + di, jj = j + dj;
    bool v = ((unsigned)ii < 24u) && ((unsigned)jj < 24u);
    sptr[s] = C1p + ((size_t)b * 576 + (size_t)(v ? (ii * 24 + jj) : ij)) * 6912;
    tb[s] = v ? s * 3 : 27;   // invalid slab -> zero-weight taps 27..29
  }

  auto STAGE = [&](const unsigned int* sp, int par) {
#pragma unroll
    for (int r = 0; r < 7; ++r) {
      const int g = w * 7 + r;                         // 0..27
      const unsigned int* gp = sp + (g < 27 ? g * 256 : 0) + lane * 4;
      async16(gp, (char*)lds + par * 28672 + g * 1024);
    }
  };

  f32x4 acc[9];
#pragma unroll
  for (int mi = 0; mi < 9; ++mi) acc[mi] = (f32x4){0.f, 0.f, 0.f, 0.f};

  STAGE(sptr[0], 0);

#pragma unroll
  for (int s = 0; s < 9; ++s) {
    const int par = s & 1;
    short8 p1[3][2], p2[3][2];
#pragma unroll
    for (int dk = 0; dk < 3; ++dk)
#pragma unroll
      for (int h = 0; h < 2; ++h) {
        size_t o = (size_t)(((tb[s] + dk) * 2 + h) * 16 + m15) * 32 + (size_t)q4 * 8;
        p1[dk][h] = *(const short8*)(Wp1 + o);
        p2[dk][h] = *(const short8*)(Wp2 + o);
      }
    if (s < 8) {
      STAGE(sptr[s + 1], par ^ 1);
      asm volatile("s_waitcnt vmcnt(7)" ::: "memory");
    } else {
      asm volatile("s_waitcnt vmcnt(0)" ::: "memory");
    }
    __builtin_amdgcn_s_barrier();
    __builtin_amdgcn_sched_barrier(0);

    const unsigned int* buf = lds + par * 7168;
#pragma unroll
    for (int dk = 0; dk < 3; ++dk) {
#pragma unroll
      for (int mi = 0; mi < 9; ++mi) {
        const char* base = (const char*)(buf + (rowb[mi] + (dk - 1) * 260)) + q4 * 16;
        uint2 a00 = *(const uint2*)(base);
        uint2 a01 = *(const uint2*)(base + 8);
        uint2 a10 = *(const uint2*)(base + 64);
        uint2 a11 = *(const uint2*)(base + 72);
        short8 a0 = __builtin_bit_cast(short8, (u32x4){a00.x, a00.y, a01.x, a01.y});
        short8 a1 = __builtin_bit_cast(short8, (u32x4){a10.x, a10.y, a11.x, a11.y});
        acc[mi] = __builtin_amdgcn_mfma_f32_16x16x32_bf16(a0, p1[dk][0], acc[mi], 0, 0, 0);
        acc[mi] = __builtin_amdgcn_mfma_f32_16x16x32_bf16(a0, p2[dk][0], acc[mi], 0, 0, 0);
        acc[mi] = __builtin_amdgcn_mfma_f32_16x16x32_bf16(a1, p1[dk][1], acc[mi], 0, 0, 0);
        acc[mi] = __builtin_amdgcn_mfma_f32_16x16x32_bf16(a1, p2[dk][1], acc[mi], 0, 0, 0);
      }
    }
    __builtin_amdgcn_sched_barrier(0);
    __builtin_amdgcn_s_barrier();
  }

  if (m15 < 10) {
    const float bv = bias[m15];
#pragma unroll
    for (int mi = 0; mi < 9; ++mi) {
#pragma unroll
      for (int reg = 0; reg < 4; ++reg) {
        int kl = (w * 9 + mi) * 16 + q4 * 4 + reg;
        int kk = kl / 24 + 1, ll = kl % 24 + 1;
        float v = fmaxf(acc[mi][reg] + bv, 0.f);
        unsigned short hi = f2bf(v);
        unsigned short lo = f2bf(v - bf2f(hi));
        yb[(kk * 26 + ll) * 10 + m15] = ((unsigned)hi << 16) | (unsigned)lo;
      }
    }
  }
}

// ---------------- K10: conv3 (10->1) via MFMA, dk-in-N (R5-exact) ----------
__global__ __launch_bounds__(256, 2) void k_conv3_mfma(
    const unsigned int* __restrict__ C2p,
    const unsigned short* __restrict__ Bh, const unsigned short* __restrict__ Bl,
    const float* __restrict__ bias, float* __restrict__ C3) {
  __shared__ __align__(16) unsigned int lds[2 * 7168];
  const int b = blockIdx.y, ij = blockIdx.x;
  const int i = ij / 24, j = ij % 24;
  const int t = threadIdx.x, lane = t & 63, w = t >> 6;
  const int m15 = lane & 15, q4 = lane >> 4;

  int rowb[10];
#pragma unroll
  for (int mi = 0; mi < 10; ++mi) {
    int m = (w * 10 + mi) * 16 + m15;
    int kp = m / 24, l = m % 24;
    rowb[mi] = (m < 624) ? (kp * 26 + l) * 10 : 0;
  }

  bool sval[9];
  const unsigned int* sptr[9];
#pragma unroll
  for (int s = 0; s < 9; ++s) {
    int di = s / 3 - 1, dj = s % 3 - 1;
    int ii = i + di, jj = j + dj;
    bool v = ((unsigned)ii < 24u) && ((unsigned)jj < 24u);
    sval[s] = v;
    sptr[s] = C2p + ((size_t)b * 576 + (size_t)(v ? (ii * 24 + jj) : ij)) * 6912;
  }

  short8 BHk[9], BLk[9];
#pragma unroll
  for (int s = 0; s < 9; ++s) {
    size_t o = (size_t)(s * 16 + m15) * 32 + (size_t)q4 * 8;
    BHk[s] = *(const short8*)(Bh + o);
    BLk[s] = *(const short8*)(Bl + o);
  }

  auto STAGE = [&](const unsigned int* sp, int par) {
#pragma unroll
    for (int r = 0; r < 7; ++r) {
      const int g = w * 7 + r;                         // 0..27
      const unsigned int* gp = sp + (g < 27 ? g * 256 : 0) + lane * 4;
      async16(gp, (char*)lds + par * 28672 + g * 1024);
    }
  };

  f32x4 acc[10];
#pragma unroll
  for (int mi = 0; mi < 10; ++mi) acc[mi] = (f32x4){0.f, 0.f, 0.f, 0.f};

  STAGE(sptr[0], 0);

#pragma unroll
  for (int s = 0; s < 9; ++s) {
    const int par = s & 1;
    if (s < 8) {
      STAGE(sptr[s + 1], par ^ 1);
      asm volatile("s_waitcnt vmcnt(7)" ::: "memory");
    } else {
      asm volatile("s_waitcnt vmcnt(0)" ::: "memory");
    }
    __builtin_amdgcn_s_barrier();
    __builtin_amdgcn_sched_barrier(0);
    if (sval[s]) {                       // block-uniform branch
      const unsigned int* buf = lds + par * 7168;
#pragma unroll
      for (int mi = 0; mi < 10; ++mi) {
        const uint2* p = (const uint2*)(buf + rowb[mi] + q4 * 8);
        uint2 d0 = p[0], d1 = p[1], d2 = p[2], d3 = p[3];
        u32x4 hd, lv;
        hd.x = __builtin_amdgcn_perm(d0.y, d0.x, 0x07060302u);
        hd.y = __builtin_amdgcn_perm(d1.y, d1.x, 0x07060302u);
        hd.z = __builtin_amdgcn_perm(d2.y, d2.x, 0x07060302u);
        hd.w = __builtin_amdgcn_perm(d3.y, d3.x, 0x07060302u);
        lv.x = __builtin_amdgcn_perm(d0.y, d0.x, 0x05040100u);
        lv.y = __builtin_amdgcn_perm(d1.y, d1.x, 0x05040100u);
        lv.z = __builtin_amdgcn_perm(d2.y, d2.x, 0x05040100u);
        lv.w = __builtin_amdgcn_perm(d3.y, d3.x, 0x05040100u);
        short8 ah = __builtin_bit_cast(short8, hd);
        short8 al = __builtin_bit_cast(short8, lv);
        acc[mi] = __builtin_amdgcn_mfma_f32_16x16x32_bf16(ah, BHk[s], acc[mi], 0, 0, 0);
        acc[mi] = __builtin_amdgcn_mfma_f32_16x16x32_bf16(ah, BLk[s], acc[mi], 0, 0, 0);
        acc[mi] = __builtin_amdgcn_mfma_f32_16x16x32_bf16(al, BHk[s], acc[mi], 0, 0, 0);
      }
    }
    __builtin_amdgcn_sched_barrier(0);
    __builtin_amdgcn_s_barrier();
  }

  float* u = (float*)lds;                // 640*4 floats = 10240 B
  if (m15 < 3) {
#pragma unroll
    for (int mi = 0; mi < 10; ++mi)
#pragma unroll
      for (int reg = 0; reg < 4; ++reg) {
        int m = (w * 10 + mi) * 16 + q4 * 4 + reg;
        u[m * 4 + m15] = acc[mi][reg];
      }
  }
  __syncthreads();
  const float bv = bias[0];
  float* outp = C3 + (size_t)b * S4 + (size_t)ij * 576;
  for (int idx = t; idx < 576; idx += 256) {
    int k = idx / 24, l = idx % 24;
    float sum = u[((k + 0) * 24 + l) * 4 + 0]
              + u[((k + 1) * 24 + l) * 4 + 1]
              + u[((k + 2) * 24 + l) * 4 + 2];
    outp[idx] = fmaxf(sum + bv, 0.f);
  }
}

// ---------------------------------------------------------------------------
extern "C" void kernel_launch(void* const* d_in, const int* in_sizes, int n_in,
                              void* d_out, int out_size, void* d_ws, size_t ws_size,
                              hipStream_t stream) {
  const float* fA = (const float*)d_in[0];
  const float* fB = (const float*)d_in[1];
  const float* w1 = (const float*)d_in[2];
  const float* b1 = (const float*)d_in[3];
  const float* w2 = (const float*)d_in[4];
  const float* b2 = (const float*)d_in[5];
  const float* w3 = (const float*)d_in[6];
  const float* b3 = (const float*)d_in[7];
  float* out = (float*)d_out;
  float* ws = (float*)d_ws;
  (void)in_sizes; (void)n_in; (void)out_size; (void)ws_size;

  // --- workspace layout (floats/dwords), peak 63,710,208 fl < R5's peak ---
  // conv2 packs live in d_out scratch (dead before final mm#2 writes out).
  unsigned int* C1p  = (unsigned int*)ws;            // 31,850,496 dw
  unsigned int* C2p  = (unsigned int*)(ws + 31850496); // 31,850,496 dw
  unsigned short* TAhi = (unsigned short*)ws;        // 4 x 18,874,368 shorts
  unsigned short* TAlo = TAhi + (size_t)8 * P_ * C_;
  unsigned short* TBhi = TAlo + (size_t)8 * P_ * C_;
  unsigned short* TBlo = TBhi + (size_t)8 * P_ * C_; // ends at fl 37,748,736
  float* pooled = ws + 37748736;                     // 2,654,208
  float* part   = ws + 40402944;                     // 589,824
  float* invn   = ws + 40992768;                     // 36,864
  float* amax1  = ws + 41029632;                     // 4,608
  float* bmax1  = ws + 41034240;                     // 4,608
  float* C3     = ws + 0;                            // 2,654,208 (over dead C1p)
  float* amax2  = ws + 2654208;
  float* bmax2  = ws + 2658816;
  unsigned short* Bh3 = (unsigned short*)(ws + 63700992);  // 4,608 shorts
  unsigned short* Bl3 = Bh3 + 4608;                        // 4,608 shorts
  unsigned short* Wp2a = (unsigned short*)d_out;           // 30,720 shorts
  unsigned short* Wp2b = Wp2a + 30720;                     // 30,720 shorts

  // 1+2) transpose/split + norms + MFMA correlation (192x96 tiles)
  k_prep<<<dim3(16, 36, 16), 256, 0, stream>>>(fA, fB, TAhi, TAlo, TBhi, TBlo, part);
  k_invnorm<<<dim3(9, 16), 256, 0, stream>>>(part, invn);
  k_corr_mfma<<<dim3(288, 8), 256, 0, stream>>>(TAhi, TAlo, TBhi, TBlo, invn, pooled);

  // 3) mutual matching #1 (in place)
  k_rowmax<<<dim3(8 * 576), 64, 0, stream>>>(pooled, amax1);
  k_colmax<<<dim3(8, 9), 256, 0, stream>>>(pooled, bmax1);
  k_mm_apply<<<dim3(10368), 256, 0, stream>>>(pooled, amax1, bmax1, pooled);

  // 4) neighbourhood consensus: conv1 (scalar, packed out) -> conv2 (MFMA,
  //    interleaved-kappa', zero-perm) -> conv3 (MFMA, R5 perm path)
  k_packw2<<<dim3(120), 256, 0, stream>>>(w2, Wp2a, Wp2b);
  k_packw3<<<dim3(18), 256, 0, stream>>>(w3, Bh3, Bl3);
  k_conv1_pack<<<dim3(576, 8), 192, 0, stream>>>(pooled, w1, b1, C1p);
  k_conv2_mfma<<<dim3(576, 8), 256, 0, stream>>>(C1p, Wp2a, Wp2b, b2, C2p);
  k_conv3_mfma<<<dim3(576, 8), 256, 0, stream>>>(C2p, Bh3, Bl3, b3, C3);

  // 5) mutual matching #2 -> final output (overwrites the pack scratch)
  k_rowmax<<<dim3(8 * 576), 64, 0, stream>>>(C3, amax2);
  k_colmax<<<dim3(8, 9), 256, 0, stream>>>(C3, bmax2);
  k_mm_apply<<<dim3(10368), 256, 0, stream>>>(C3, amax2, bmax2, out);
}

// Round 9
// 983.616 us; speedup vs baseline: 1.0348x; 1.0348x over previous
//
#include <hip/hip_runtime.h>
#include <hip/hip_bf16.h>
#include <math.h>

#define C_   1024
#define P_   2304      // 48*48
#define S4   331776    // 24^4

typedef __attribute__((ext_vector_type(8))) short short8;
typedef __attribute__((ext_vector_type(4))) float f32x4;
typedef __attribute__((ext_vector_type(4))) unsigned int u32x4;

__device__ inline unsigned short f2bf(float v) {
  unsigned u = __builtin_bit_cast(unsigned, v);
  u += 0x7fffu + ((u >> 16) & 1u);          // RNE
  return (unsigned short)(u >> 16);
}
__device__ inline float bf2f(unsigned short h) {
  unsigned u = ((unsigned)h) << 16;
  return __builtin_bit_cast(float, u);
}

// async global->LDS DMA, 16B per lane; LDS dest = wave-uniform base + lane*16
__device__ inline void async16(const void* g, void* l) {
  __builtin_amdgcn_global_load_lds(
      (const __attribute__((address_space(1))) unsigned int*)g,
      (__attribute__((address_space(3))) unsigned int*)l, 16, 0, 0);
}

// ---------------- K1: transpose + bf16 hi/lo split + sumsq partials --------
__global__ __launch_bounds__(256) void k_prep(
    const float* __restrict__ fA, const float* __restrict__ fB,
    unsigned short* __restrict__ TAhi, unsigned short* __restrict__ TAlo,
    unsigned short* __restrict__ TBhi, unsigned short* __restrict__ TBlo,
    float* __restrict__ part) {
  __shared__ float ld[64 * 65];
  __shared__ float pslds[512];
  const int c0 = blockIdx.x * 64, p0 = blockIdx.y * 64;
  const int fb = blockIdx.z, f = fb >> 3, b = fb & 7;
  const float* src = (f ? fB : fA) + (size_t)b * C_ * P_;
  unsigned short* Thi = (f ? TBhi : TAhi) + (size_t)b * P_ * C_;
  unsigned short* Tlo = (f ? TBlo : TAlo) + (size_t)b * P_ * C_;
  const int t = threadIdx.x;
#pragma unroll
  for (int e = 0; e < 4; ++e) {
    int cid = t + e * 256;
    int r = cid >> 4, ch = cid & 15;
    float4 v = *(const float4*)&src[(size_t)(c0 + r) * P_ + p0 + ch * 4];
    ld[r * 65 + ch * 4 + 0] = v.x;
    ld[r * 65 + ch * 4 + 1] = v.y;
    ld[r * 65 + ch * 4 + 2] = v.z;
    ld[r * 65 + ch * 4 + 3] = v.w;
  }
  __syncthreads();
#pragma unroll
  for (int e = 0; e < 2; ++e) {
    int ocid = t + e * 256;
    int pl = ocid >> 3, c8 = ocid & 7;
    unsigned short hi[8], lo[8];
    float sq = 0.f;
#pragma unroll
    for (int s = 0; s < 8; ++s) {
      float v = ld[(c8 * 8 + s) * 65 + pl];
      unsigned short h = f2bf(v);
      float rem = v - bf2f(h);
      hi[s] = h; lo[s] = f2bf(rem);
      sq = fmaf(v, v, sq);
    }
    size_t go = (size_t)(p0 + pl) * C_ + c0 + c8 * 8;
    *(uint4*)&Thi[go] = *(uint4*)hi;
    *(uint4*)&Tlo[go] = *(uint4*)lo;
    pslds[ocid] = sq;
  }
  __syncthreads();
  if (t < 64) {
    float s = 0.f;
#pragma unroll
    for (int c8 = 0; c8 < 8; ++c8) s += pslds[t * 8 + c8];
    part[((size_t)fb * 16 + blockIdx.x) * P_ + p0 + t] = s;
  }
}

// ---------------- K2: finalize inverse norms -------------------------------
__global__ void k_invnorm(const float* __restrict__ part, float* __restrict__ inv) {
  int p = blockIdx.x * 256 + threadIdx.x;
  int fb = blockIdx.y;
  float s = 1e-6f;
  for (int ct = 0; ct < 16; ++ct) s += part[((size_t)fb * 16 + ct) * P_ + p];
  inv[(size_t)fb * P_ + p] = 1.0f / sqrtf(s);
}

// ---------------- K3: bf16x3 MFMA correlation + relu/norm/4D-maxpool -------
// v5 structure (R5, verified): 192x96 tile, XOR-chunk swizzled staging,
// pre-reduced epilogue. Unchanged.
__global__ __launch_bounds__(256, 3) void k_corr_mfma(
    const unsigned short* __restrict__ TAhi_, const unsigned short* __restrict__ TAlo_,
    const unsigned short* __restrict__ TBhi_, const unsigned short* __restrict__ TBlo_,
    const float* __restrict__ invn, float* __restrict__ pooled) {
  __shared__ __align__(16) char lds_raw[36864];   // 576 rows x 64 B; epi overlay
  float* epi = (float*)lds_raw;                   // [96][50] f32 = 19200 B

  const int b = blockIdx.y;
  const size_t tb = (size_t)b * P_ * C_;
  const unsigned short* TAhi = TAhi_ + tb;
  const unsigned short* TAlo = TAlo_ + tb;
  const unsigned short* TBhi = TBhi_ + tb;
  const unsigned short* TBlo = TBlo_ + tb;
  float* out = pooled + (size_t)b * S4;

  const int g = blockIdx.x;                 // 0..287
  const int xcd = g & 7, idx = g >> 3;      // idx 0..35
  const int ti = (xcd & 1) * 6 + idx % 6;   // 0..11
  const int tj = (xcd >> 1) * 6 + idx / 6;  // 0..23
  const int p0 = ti * 192, q0 = tj * 96;
  const int t = threadIdx.x;
  const int lane = t & 63, w = t >> 6;
  const int wr = w >> 1, wc = w & 1;
  const int m15 = lane & 15, q4 = lane >> 4;
  const int laneoff = (q4 ^ ((m15 >> 1) & 3)) * 16;

  f32x4 acc[6][3];
#pragma unroll
  for (int a = 0; a < 6; ++a)
#pragma unroll
    for (int c = 0; c < 3; ++c) acc[a][c] = (f32x4){0.f, 0.f, 0.f, 0.f};

  const unsigned short* gld[9];
  int ldsb[9];
#pragma unroll
  for (int e = 0; e < 9; ++e) {
    int chunk = (w * 9 + e) * 64 + lane;    // 0..2303
    int row = chunk >> 2, cpos = chunk & 3;
    int cglob = cpos ^ ((row >> 1) & 3);
    const unsigned short* bp; int roff;
    if (row < 192)      { bp = TAhi; roff = p0 + row; }
    else if (row < 384) { bp = TAlo; roff = p0 + row - 192; }
    else if (row < 480) { bp = TBhi; roff = q0 + row - 384; }
    else                { bp = TBlo; roff = q0 + row - 480; }
    gld[e] = bp + (size_t)roff * C_ + cglob * 8;
    ldsb[e] = (w * 9 + e) * 1024;
  }

  auto STAGE = [&](int kt) {
#pragma unroll
    for (int e = 0; e < 9; ++e)
      async16(gld[e] + kt, lds_raw + ldsb[e]);
  };

  for (int kt = 0; kt < C_; kt += 32) {
    __syncthreads();
    STAGE(kt);
    asm volatile("s_waitcnt vmcnt(0)" ::: "memory");
    __syncthreads();

    const char* buf = lds_raw;
    short8 bh[3], bl[3];
#pragma unroll
    for (int c = 0; c < 3; ++c) {
      int rB = (384 + wc * 48 + c * 16 + m15) * 64;
      bh[c] = *(const short8*)(buf + rB + laneoff);
      bl[c] = *(const short8*)(buf + rB + 6144 + laneoff);
    }
#pragma unroll
    for (int a = 0; a < 6; ++a) {
      int rA = (wr * 96 + a * 16 + m15) * 64;
      short8 ah = *(const short8*)(buf + rA + laneoff);
      short8 al = *(const short8*)(buf + rA + 12288 + laneoff);
#pragma unroll
      for (int c = 0; c < 3; ++c)
        acc[a][c] = __builtin_amdgcn_mfma_f32_16x16x32_bf16(ah, bh[c], acc[a][c], 0, 0, 0);
#pragma unroll
      for (int c = 0; c < 3; ++c)
        acc[a][c] = __builtin_amdgcn_mfma_f32_16x16x32_bf16(ah, bl[c], acc[a][c], 0, 0, 0);
#pragma unroll
      for (int c = 0; c < 3; ++c)
        acc[a][c] = __builtin_amdgcn_mfma_f32_16x16x32_bf16(al, bh[c], acc[a][c], 0, 0, 0);
    }
  }
  __syncthreads();

  const float* invA = invn + (size_t)b * P_;
  const float* invB = invn + (size_t)(8 + b) * P_;
  float ibv[3];
#pragma unroll
  for (int c = 0; c < 3; ++c) ibv[c] = invB[q0 + wc * 48 + c * 16 + m15];
#pragma unroll
  for (int a = 0; a < 6; ++a) {
    float4 ia = *(const float4*)&invA[p0 + wr * 96 + a * 16 + q4 * 4];
    int h_local = wr * 2 + (a >= 3 ? 1 : 0);
    int wbase = (a % 3) * 8 + q4 * 2;
#pragma unroll
    for (int c = 0; c < 3; ++c) {
      float v0 = acc[a][c][0] * ia.x * ibv[c];
      float v1 = acc[a][c][1] * ia.y * ibv[c];
      float v2 = acc[a][c][2] * ia.z * ibv[c];
      float v3 = acc[a][c][3] * ia.w * ibv[c];
      float m0 = fmaxf(v0, v1), m1 = fmaxf(v2, v3);
      m0 = fmaxf(m0, __shfl_xor(m0, 1, 64));
      m1 = fmaxf(m1, __shfl_xor(m1, 1, 64));
      if (!(m15 & 1)) {
        int ql2 = wc * 24 + c * 8 + (m15 >> 1);
        epi[(h_local * 24 + wbase + 0) * 50 + ql2] = m0;
        epi[(h_local * 24 + wbase + 1) * 50 + ql2] = m1;
      }
    }
  }
  __syncthreads();

  for (int ix = t; ix < 1152; ix += 256) {
    int orow = ix / 24, ocol = ix % 24;
    int dlt = orow / 24, wp = orow % 24;
    const float* r0 = &epi[((dlt * 2 + 0) * 24 + wp) * 50];
    const float* r1 = &epi[((dlt * 2 + 1) * 24 + wp) * 50];
    float m = fmaxf(fmaxf(r0[ocol], r0[24 + ocol]),
                    fmaxf(r1[ocol], r1[24 + ocol]));
    float r = fmaxf(m, 0.f);
    float v = r / sqrtf(r * r + 1e-6f);
    out[(size_t)(ti * 48 + orow) * 576 + tj * 24 + ocol] = v;
  }
}

// ---------------- K4a: row max (over kl, per ij) ---------------------------
__global__ void k_rowmax(const float* __restrict__ x, float* __restrict__ amax) {
  int row = blockIdx.x;
  const float* r = x + (size_t)row * 576;
  float m = -1e30f;
  for (int e = threadIdx.x; e < 576; e += 64) m = fmaxf(m, r[e]);
  for (int off = 32; off > 0; off >>= 1) m = fmaxf(m, __shfl_down(m, off, 64));
  if (threadIdx.x == 0) amax[row] = m;
}

// ---------------- K4b: col max (over ij, per kl) ---------------------------
__global__ void k_colmax(const float* __restrict__ x, float* __restrict__ bmax) {
  __shared__ float pl[4][64];
  int b = blockIdx.x, klc = blockIdx.y * 64;
  int t = threadIdx.x;
  int kl = klc + (t & 63), seg = t >> 6;
  const float* xb = x + (size_t)b * S4;
  float m = -1e30f;
  for (int ij = seg * 144; ij < (seg + 1) * 144; ++ij)
    m = fmaxf(m, xb[(size_t)ij * 576 + kl]);
  pl[seg][t & 63] = m;
  __syncthreads();
  if (t < 64) {
    float r = fmaxf(fmaxf(pl[0][t], pl[1][t]), fmaxf(pl[2][t], pl[3][t]));
    bmax[b * 576 + klc + t] = r;
  }
}

// ---------------- K5: mutual matching elementwise --------------------------
__global__ void k_mm_apply(const float* __restrict__ x,
                           const float* __restrict__ amax,
                           const float* __restrict__ bmax,
                           float* __restrict__ y) {
  int i = blockIdx.x * 256 + threadIdx.x;
  int b = i / S4, r = i % S4;
  int ij = r / 576, kl = r % 576;
  float c = x[i];
  y[i] = c * (c / (amax[b * 576 + ij] + 1e-5f)) * (c / (bmax[b * 576 + kl] + 1e-5f));
}

// ---------------- K7: conv1 (CIN=1, COUT=10) -> packed halo layout ---------
__global__ __launch_bounds__(192, 4) void k_conv1_pack(
    const float* __restrict__ x, const float* __restrict__ w,
    const float* __restrict__ bias, unsigned int* __restrict__ C1p) {
  __shared__ float tile[9 * 702];
  const float* xb = x + (size_t)S4 * blockIdx.y;
  unsigned int* yb = C1p + ((size_t)blockIdx.y * 576 + blockIdx.x) * 6912;
  const int ij = blockIdx.x;
  const int i = ij / 24, j = ij % 24;
  const int t = threadIdx.x;
  const int k = t >> 3;
  const int l0 = (t & 7) * 3;

  if (t < 152) yb[6760 + t] = 0u;
  if (t < 100) {
    int kk, ll;
    if (t < 26)      { kk = 0;          ll = t; }
    else if (t < 52) { kk = 25;         ll = t - 26; }
    else if (t < 76) { kk = t - 52 + 1; ll = 0; }
    else             { kk = t - 76 + 1; ll = 25; }
    unsigned int* p = yb + (kk * 26 + ll) * 10;
#pragma unroll
    for (int q = 0; q < 10; ++q) p[q] = 0u;
  }

  int soff[4]; bool eok[4], klok[4]; int eidx[4];
#pragma unroll
  for (int q = 0; q < 4; ++q) {
    int e = t + q * 192;
    eidx[q] = e; eok[q] = (e < 702);
    int row = e / 27, col = e % 27;
    klok[q] = (row >= 1 && row < 25 && col >= 1 && col < 25);
    soff[q] = (row - 1) * 24 + (col - 1);
  }

  float acc[10][3];
#pragma unroll
  for (int co = 0; co < 10; ++co)
#pragma unroll
    for (int oo = 0; oo < 3; ++oo) acc[co][oo] = 0.f;

#pragma unroll
  for (int pln = 0; pln < 9; ++pln) {
    int ii = i + pln / 3 - 1, jj = j + pln % 3 - 1;
    const bool slab_ok = (ii >= 0 && ii < 24 && jj >= 0 && jj < 24);
    const float* src = xb + (size_t)(ii * 24 + jj) * 576;
#pragma unroll
    for (int q = 0; q < 4; ++q) {
      if (eok[q]) {
        float v = 0.f;
        if (slab_ok && klok[q]) v = src[soff[q]];
        tile[pln * 702 + eidx[q]] = v;
      }
    }
  }
  __syncthreads();
#pragma unroll
  for (int pln = 0; pln < 9; ++pln) {
    const float* base = &tile[pln * 702 + k * 27 + l0];
#pragma unroll
    for (int dk = 0; dk < 3; ++dk) {
      float c0 = base[dk * 27 + 0], c1 = base[dk * 27 + 1],
            c2 = base[dk * 27 + 2], c3 = base[dk * 27 + 3],
            c4 = base[dk * 27 + 4];
#pragma unroll
      for (int co = 0; co < 10; ++co) {
        const float* wr = w + (size_t)co * 81 + pln * 9 + dk * 3;
        float w0 = wr[0], w1 = wr[1], w2v = wr[2];
        acc[co][0] = fmaf(w0, c0, acc[co][0]);
        acc[co][0] = fmaf(w1, c1, acc[co][0]);
        acc[co][0] = fmaf(w2v, c2, acc[co][0]);
        acc[co][1] = fmaf(w0, c1, acc[co][1]);
        acc[co][1] = fmaf(w1, c2, acc[co][1]);
        acc[co][1] = fmaf(w2v, c3, acc[co][1]);
        acc[co][2] = fmaf(w0, c2, acc[co][2]);
        acc[co][2] = fmaf(w1, c3, acc[co][2]);
        acc[co][2] = fmaf(w2v, c4, acc[co][2]);
      }
    }
  }
#pragma unroll
  for (int oo = 0; oo < 3; ++oo) {
    unsigned int* baseo = yb + ((k + 1) * 26 + (l0 + oo + 1)) * 10;
#pragma unroll
    for (int co = 0; co < 10; ++co) {
      float v = fmaxf(acc[co][oo] + bias[co], 0.f);
      unsigned short hi = f2bf(v);
      unsigned short lo = f2bf(v - bf2f(hi));
      baseo[co] = ((unsigned)hi << 16) | (unsigned)lo;
    }
  }
}

// ---------------- K8: pack conv2 weights (dk-in-N, interleaved-kappa') -----
// P1/P2: [9 slabs][2 groups][2 half][16 n][32 kappa'] ushort.
// n = co_in_group*3 + dk (15 used); co = g*5 + co_in_group.
// Real k = h*16 + kp/2 (30 used); dl = k/10, ci = k%10.
// P1[kp] = Wh[k] both parities -> (lo+hi)*Wh = A*Wh ; P2[kp] = odd ? Wl : 0.
__global__ void k_packw2(const float* __restrict__ w2,
                         unsigned short* __restrict__ P1,
                         unsigned short* __restrict__ P2) {
  int idx = blockIdx.x * 256 + threadIdx.x;
  if (idx >= 18432) return;
  int s  = idx >> 11;             // slab 0..8
  int g  = (idx >> 10) & 1;
  int h  = (idx >> 9) & 1;
  int n  = (idx >> 5) & 15;
  int kp = idx & 31;
  int k  = h * 16 + (kp >> 1);
  float v = 0.f;
  if (n < 15 && k < 30) {
    int cop = n / 3, dk = n % 3;
    int co = g * 5 + cop;
    int ci = k % 10, dl = k / 10;
    v = w2[(size_t)(co * 10 + ci) * 81 + s * 9 + dk * 3 + dl];
  }
  unsigned short hi = f2bf(v);
  unsigned short lo = f2bf(v - bf2f(hi));
  P1[idx] = hi;
  P2[idx] = (kp & 1) ? lo : (unsigned short)0;
}

// ---------------- K8b: pack conv3 weights (R5 layout, perms path) ----------
__global__ void k_packw3(const float* __restrict__ w3,
                         unsigned short* __restrict__ Bh,
                         unsigned short* __restrict__ Bl) {
  int idx = blockIdx.x * 256 + threadIdx.x;
  if (idx >= 4608) return;
  int s = idx >> 9;            // slab (di,dj) 0..8
  int n = (idx >> 5) & 15;     // dk
  int kap = idx & 31;
  float v = 0.f;
  if (n < 3 && kap < 30) {
    int ci = kap % 10, dl = kap / 10;
    v = w3[(size_t)ci * 81 + s * 9 + n * 3 + dl];
  }
  unsigned short hi = f2bf(v);
  unsigned short lo = f2bf(v - bf2f(hi));
  Bh[idx] = hi; Bl[idx] = lo;
}

// ---------------- K9: conv2 (10->10) MFMA, dk-in-N + zero-perm -------------
// M = 624 padded positions (kp 0..25, l 0..23), 10 tiles of 16 per wave.
// N = 15 (5 co x 3 dk) per group, 2 groups. K-window read ONCE per (mi,slab)
// (vs 3x in the dk-in-tap version): LDS reads 108->40 b64 per wave-slab.
// acc[10][2] f32x4 in regs across slabs; two-pass LDS stage-2 (u[640][15],
// 38.4 KB overlay) does the dk shift-sum + bias + relu + pack (conv3's
// verified geometry). XCD-chunked swizzle: ij = (x&7)*72 + (x>>3) -> each
// XCD owns 3 contiguous i-rows -> halo slabs L2-resident.
// vmcnt: per-iter issue = [8 B-loads][7 STAGE]; vmcnt(7) leaves only
// STAGE(s+1) in flight. Tail vmcnt(0).
__global__ __launch_bounds__(256, 2) void k_conv2_mfma(
    const unsigned int* __restrict__ C1p,
    const unsigned short* __restrict__ Wp1, const unsigned short* __restrict__ Wp2,
    const float* __restrict__ bias, unsigned int* __restrict__ C2p) {
  __shared__ __align__(16) unsigned int lds[2 * 7168];
  const int b = blockIdx.y;
  const int x = blockIdx.x;
  const int ij = (x & 7) * 72 + (x >> 3);          // bijective XCD chunking
  const int i = ij / 24, j = ij % 24;
  const int t = threadIdx.x, lane = t & 63, w = t >> 6;
  const int m15 = lane & 15, q4 = lane >> 4;

  // zero halo border + pad of own output slab (block-owned, disjoint addrs)
  unsigned int* yb = C2p + ((size_t)b * 576 + ij) * 6912;
  if (t < 152) yb[6760 + t] = 0u;
  if (t < 100) {
    int kk, ll;
    if (t < 26)      { kk = 0;          ll = t; }
    else if (t < 52) { kk = 25;         ll = t - 26; }
    else if (t < 76) { kk = t - 52 + 1; ll = 0; }
    else             { kk = t - 76 + 1; ll = 25; }
    unsigned int* p = yb + (kk * 26 + ll) * 10;
#pragma unroll
    for (int q = 0; q < 10; ++q) p[q] = 0u;
  }

  // A row bases: m = kp*24 + l; tail m>=624 clamped (discarded in stage 2)
  int rowb[10];
#pragma unroll
  for (int mi = 0; mi < 10; ++mi) {
    int m = (w * 10 + mi) * 16 + m15;
    int kp = m / 24, l = m % 24;
    rowb[mi] = (m < 624) ? (kp * 26 + l) * 10 : 0;
  }

  bool sval[9];
  const unsigned int* sptr[9];
#pragma unroll
  for (int s = 0; s < 9; ++s) {
    int di = s / 3 - 1, dj = s % 3 - 1;
    int ii = i + di, jj = j + dj;
    bool v = ((unsigned)ii < 24u) && ((unsigned)jj < 24u);
    sval[s] = v;
    sptr[s] = C1p + ((size_t)b * 576 + (size_t)(v ? (ii * 24 + jj) : ij)) * 6912;
  }

  auto STAGE = [&](const unsigned int* sp, int par) {
#pragma unroll
    for (int r = 0; r < 7; ++r) {
      const int g = w * 7 + r;                         // 0..27
      const unsigned int* gp = sp + (g < 27 ? g * 256 : 0) + lane * 4;
      async16(gp, (char*)lds + par * 28672 + g * 1024);
    }
  };

  f32x4 acc[10][2];
#pragma unroll
  for (int mi = 0; mi < 10; ++mi)
#pragma unroll
    for (int g = 0; g < 2; ++g) acc[mi][g] = (f32x4){0.f, 0.f, 0.f, 0.f};

  STAGE(sptr[0], 0);

#pragma unroll
  for (int s = 0; s < 9; ++s) {
    const int par = s & 1;
    short8 p1[2][2], p2[2][2];                 // [group][half]
#pragma unroll
    for (int g = 0; g < 2; ++g)
#pragma unroll
      for (int h = 0; h < 2; ++h) {
        size_t o = (size_t)((((s * 2 + g) * 2 + h) * 16) + m15) * 32 + (size_t)q4 * 8;
        p1[g][h] = *(const short8*)(Wp1 + o);
        p2[g][h] = *(const short8*)(Wp2 + o);
      }
    if (s < 8) {
      STAGE(sptr[s + 1], par ^ 1);
      asm volatile("s_waitcnt vmcnt(7)" ::: "memory");
    } else {
      asm volatile("s_waitcnt vmcnt(0)" ::: "memory");
    }
    __builtin_amdgcn_s_barrier();
    __builtin_amdgcn_sched_barrier(0);

    if (sval[s]) {                       // block-uniform branch
      const unsigned int* buf = lds + par * 7168;
#pragma unroll
      for (int mi = 0; mi < 10; ++mi) {
        const char* base = (const char*)(buf + rowb[mi]) + q4 * 16;
        uint2 a00 = *(const uint2*)(base);
        uint2 a01 = *(const uint2*)(base + 8);
        uint2 a10 = *(const uint2*)(base + 64);
        uint2 a11 = *(const uint2*)(base + 72);
        short8 a0 = __builtin_bit_cast(short8, (u32x4){a00.x, a00.y, a01.x, a01.y});
        short8 a1 = __builtin_bit_cast(short8, (u32x4){a10.x, a10.y, a11.x, a11.y});
#pragma unroll
        for (int g = 0; g < 2; ++g) {
          acc[mi][g] = __builtin_amdgcn_mfma_f32_16x16x32_bf16(a0, p1[g][0], acc[mi][g], 0, 0, 0);
          acc[mi][g] = __builtin_amdgcn_mfma_f32_16x16x32_bf16(a0, p2[g][0], acc[mi][g], 0, 0, 0);
          acc[mi][g] = __builtin_amdgcn_mfma_f32_16x16x32_bf16(a1, p1[g][1], acc[mi][g], 0, 0, 0);
          acc[mi][g] = __builtin_amdgcn_mfma_f32_16x16x32_bf16(a1, p2[g][1], acc[mi][g], 0, 0, 0);
        }
      }
    }
    __builtin_amdgcn_sched_barrier(0);
    __builtin_amdgcn_s_barrier();
  }

  // ---- stage 2: two passes (one per co-group), u[640][15] f32 overlay ----
  float* u = (float*)lds;                          // 38,400 B
#pragma unroll
  for (int g = 0; g < 2; ++g) {
    __syncthreads();                               // prev reads done
    if (m15 < 15) {
#pragma unroll
      for (int mi = 0; mi < 10; ++mi)
#pragma unroll
        for (int reg = 0; reg < 4; ++reg) {
          int m = (w * 10 + mi) * 16 + q4 * 4 + reg;
          u[m * 15 + m15] = acc[mi][g][reg];
        }
    }
    __syncthreads();
    for (int idx = t; idx < 2880; idx += 256) {
      int cop = idx / 576;                         // 0..4
      int co = g * 5 + cop;
      int r = idx % 576;
      int k = r / 24, l = r % 24;
      float s = bias[co];
#pragma unroll
      for (int dk = 0; dk < 3; ++dk)
        s += u[((k + dk) * 24 + l) * 15 + cop * 3 + dk];
      float v = fmaxf(s, 0.f);
      unsigned short hi = f2bf(v);
      unsigned short lo = f2bf(v - bf2f(hi));
      yb[((k + 1) * 26 + (l + 1)) * 10 + co] = ((unsigned)hi << 16) | (unsigned)lo;
    }
  }
}

// ---------------- K10: conv3 (10->1) via MFMA, dk-in-N (R5-exact) ----------
__global__ __launch_bounds__(256, 2) void k_conv3_mfma(
    const unsigned int* __restrict__ C2p,
    const unsigned short* __restrict__ Bh, const unsigned short* __restrict__ Bl,
    const float* __restrict__ bias, float* __restrict__ C3) {
  __shared__ __align__(16) unsigned int lds[2 * 7168];
  const int b = blockIdx.y, ij = blockIdx.x;
  const int i = ij / 24, j = ij % 24;
  const int t = threadIdx.x, lane = t & 63, w = t >> 6;
  const int m15 = lane & 15, q4 = lane >> 4;

  int rowb[10];
#pragma unroll
  for (int mi = 0; mi < 10; ++mi) {
    int m = (w * 10 + mi) * 16 + m15;
    int kp = m / 24, l = m % 24;
    rowb[mi] = (m < 624) ? (kp * 26 + l) * 10 : 0;
  }

  bool sval[9];
  const unsigned int* sptr[9];
#pragma unroll
  for (int s = 0; s < 9; ++s) {
    int di = s / 3 - 1, dj = s % 3 - 1;
    int ii = i + di, jj = j + dj;
    bool v = ((unsigned)ii < 24u) && ((unsigned)jj < 24u);
    sval[s] = v;
    sptr[s] = C2p + ((size_t)b * 576 + (size_t)(v ? (ii * 24 + jj) : ij)) * 6912;
  }

  short8 BHk[9], BLk[9];
#pragma unroll
  for (int s = 0; s < 9; ++s) {
    size_t o = (size_t)(s * 16 + m15) * 32 + (size_t)q4 * 8;
    BHk[s] = *(const short8*)(Bh + o);
    BLk[s] = *(const short8*)(Bl + o);
  }

  auto STAGE = [&](const unsigned int* sp, int par) {
#pragma unroll
    for (int r = 0; r < 7; ++r) {
      const int g = w * 7 + r;                         // 0..27
      const unsigned int* gp = sp + (g < 27 ? g * 256 : 0) + lane * 4;
      async16(gp, (char*)lds + par * 28672 + g * 1024);
    }
  };

  f32x4 acc[10];
#pragma unroll
  for (int mi = 0; mi < 10; ++mi) acc[mi] = (f32x4){0.f, 0.f, 0.f, 0.f};

  STAGE(sptr[0], 0);

#pragma unroll
  for (int s = 0; s < 9; ++s) {
    const int par = s & 1;
    if (s < 8) {
      STAGE(sptr[s + 1], par ^ 1);
      asm volatile("s_waitcnt vmcnt(7)" ::: "memory");
    } else {
      asm volatile("s_waitcnt vmcnt(0)" ::: "memory");
    }
    __builtin_amdgcn_s_barrier();
    __builtin_amdgcn_sched_barrier(0);
    if (sval[s]) {                       // block-uniform branch
      const unsigned int* buf = lds + par * 7168;
#pragma unroll
      for (int mi = 0; mi < 10; ++mi) {
        const uint2* p = (const uint2*)(buf + rowb[mi] + q4 * 8);
        uint2 d0 = p[0], d1 = p[1], d2 = p[2], d3 = p[3];
        u32x4 hd, lv;
        hd.x = __builtin_amdgcn_perm(d0.y, d0.x, 0x07060302u);
        hd.y = __builtin_amdgcn_perm(d1.y, d1.x, 0x07060302u);
        hd.z = __builtin_amdgcn_perm(d2.y, d2.x, 0x07060302u);
        hd.w = __builtin_amdgcn_perm(d3.y, d3.x, 0x07060302u);
        lv.x = __builtin_amdgcn_perm(d0.y, d0.x, 0x05040100u);
        lv.y = __builtin_amdgcn_perm(d1.y, d1.x, 0x05040100u);
        lv.z = __builtin_amdgcn_perm(d2.y, d2.x, 0x05040100u);
        lv.w = __builtin_amdgcn_perm(d3.y, d3.x, 0x05040100u);
        short8 ah = __builtin_bit_cast(short8, hd);
        short8 al = __builtin_bit_cast(short8, lv);
        acc[mi] = __builtin_amdgcn_mfma_f32_16x16x32_bf16(ah, BHk[s], acc[mi], 0, 0, 0);
        acc[mi] = __builtin_amdgcn_mfma_f32_16x16x32_bf16(ah, BLk[s], acc[mi], 0, 0, 0);
        acc[mi] = __builtin_amdgcn_mfma_f32_16x16x32_bf16(al, BHk[s], acc[mi], 0, 0, 0);
      }
    }
    __builtin_amdgcn_sched_barrier(0);
    __builtin_amdgcn_s_barrier();
  }

  float* u = (float*)lds;                // 640*4 floats = 10240 B
  if (m15 < 3) {
#pragma unroll
    for (int mi = 0; mi < 10; ++mi)
#pragma unroll
      for (int reg = 0; reg < 4; ++reg) {
        int m = (w * 10 + mi) * 16 + q4 * 4 + reg;
        u[m * 4 + m15] = acc[mi][reg];
      }
  }
  __syncthreads();
  const float bv = bias[0];
  float* outp = C3 + (size_t)b * S4 + (size_t)ij * 576;
  for (int idx = t; idx < 576; idx += 256) {
    int k = idx / 24, l = idx % 24;
    float sum = u[((k + 0) * 24 + l) * 4 + 0]
              + u[((k + 1) * 24 + l) * 4 + 1]
              + u[((k + 2) * 24 + l) * 4 + 2];
    outp[idx] = fmaxf(sum + bv, 0.f);
  }
}

// ---------------------------------------------------------------------------
extern "C" void kernel_launch(void* const* d_in, const int* in_sizes, int n_in,
                              void* d_out, int out_size, void* d_ws, size_t ws_size,
                              hipStream_t stream) {
  const float* fA = (const float*)d_in[0];
  const float* fB = (const float*)d_in[1];
  const float* w1 = (const float*)d_in[2];
  const float* b1 = (const float*)d_in[3];
  const float* w2 = (const float*)d_in[4];
  const float* b2 = (const float*)d_in[5];
  const float* w3 = (const float*)d_in[6];
  const float* b3 = (const float*)d_in[7];
  float* out = (float*)d_out;
  float* ws = (float*)d_ws;
  (void)in_sizes; (void)n_in; (void)out_size; (void)ws_size;

  // --- workspace layout (floats/dwords), peak = R7's verified footprint ---
  // conv2 packs live in d_out scratch (dead before final mm#2 writes out).
  unsigned int* C1p  = (unsigned int*)ws;            // 31,850,496 dw
  unsigned int* C2p  = (unsigned int*)(ws + 31850496); // 31,850,496 dw
  unsigned short* TAhi = (unsigned short*)ws;        // 4 x 18,874,368 shorts
  unsigned short* TAlo = TAhi + (size_t)8 * P_ * C_;
  unsigned short* TBhi = TAlo + (size_t)8 * P_ * C_;
  unsigned short* TBlo = TBhi + (size_t)8 * P_ * C_; // ends at fl 37,748,736
  float* pooled = ws + 37748736;                     // 2,654,208
  float* part   = ws + 40402944;                     // 589,824
  float* invn   = ws + 40992768;                     // 36,864
  float* amax1  = ws + 41029632;                     // 4,608
  float* bmax1  = ws + 41034240;                     // 4,608
  float* C3     = ws + 0;                            // 2,654,208 (over dead C1p)
  float* amax2  = ws + 2654208;
  float* bmax2  = ws + 2658816;
  unsigned short* Bh3 = (unsigned short*)(ws + 63700992);  // 4,608 shorts
  unsigned short* Bl3 = Bh3 + 4608;                        // 4,608 shorts
  unsigned short* Wp2a = (unsigned short*)d_out;           // 18,432 shorts
  unsigned short* Wp2b = Wp2a + 18432;                     // 18,432 shorts

  // 1+2) transpose/split + norms + MFMA correlation (192x96 tiles)
  k_prep<<<dim3(16, 36, 16), 256, 0, stream>>>(fA, fB, TAhi, TAlo, TBhi, TBlo, part);
  k_invnorm<<<dim3(9, 16), 256, 0, stream>>>(part, invn);
  k_corr_mfma<<<dim3(288, 8), 256, 0, stream>>>(TAhi, TAlo, TBhi, TBlo, invn, pooled);

  // 3) mutual matching #1 (in place)
  k_rowmax<<<dim3(8 * 576), 64, 0, stream>>>(pooled, amax1);
  k_colmax<<<dim3(8, 9), 256, 0, stream>>>(pooled, bmax1);
  k_mm_apply<<<dim3(10368), 256, 0, stream>>>(pooled, amax1, bmax1, pooled);

  // 4) neighbourhood consensus: conv1 (scalar, packed out) -> conv2 (MFMA,
  //    dk-in-N, zero-perm, XCD-chunked) -> conv3 (MFMA, R5 perm path)
  k_packw2<<<dim3(72), 256, 0, stream>>>(w2, Wp2a, Wp2b);
  k_packw3<<<dim3(18), 256, 0, stream>>>(w3, Bh3, Bl3);
  k_conv1_pack<<<dim3(576, 8), 192, 0, stream>>>(pooled, w1, b1, C1p);
  k_conv2_mfma<<<dim3(576, 8), 256, 0, stream>>>(C1p, Wp2a, Wp2b, b2, C2p);
  k_conv3_mfma<<<dim3(576, 8), 256, 0, stream>>>(C2p, Bh3, Bl3, b3, C3);

  // 5) mutual matching #2 -> final output (overwrites the pack scratch)
  k_rowmax<<<dim3(8 * 576), 64, 0, stream>>>(C3, amax2);
  k_colmax<<<dim3(8, 9), 256, 0, stream>>>(C3, bmax2);
  k_mm_apply<<<dim3(10368), 256, 0, stream>>>(C3, amax2, bmax2, out);
}